// Round 4
// baseline (1159.298 us; speedup 1.0000x reference)
//
#include <hip/hip_runtime.h>
#include <hip/hip_bf16.h>

// Sizes from the reference
#define NSEQ   32
#define SEQLEN 256
#define NB     16    // batch
#define NIN    32
#define NH     256
#define G4     1024  // 4*H

typedef __attribute__((ext_vector_type(8))) short bf16x8;
typedef __attribute__((ext_vector_type(4))) float f32x4;
typedef unsigned long long ull;

__device__ __forceinline__ unsigned short f2bf(float f) {
    union { float f; unsigned u; } v; v.f = f;
    unsigned u = v.u;
    return (unsigned short)((u + 0x7FFFu + ((u >> 16) & 1u)) >> 16);  // RNE
}
__device__ __forceinline__ float bf2f(unsigned short u) {
    union { unsigned u; float f; } v; v.u = ((unsigned)u) << 16; return v.f;
}
__device__ __forceinline__ float sigf(float x) { return 1.0f / (1.0f + __expf(-x)); }
__device__ __forceinline__ float tanhfast(float x) { return 1.0f - 2.0f / (__expf(2.0f * x) + 1.0f); }

// ---------------- Prologue: pack weights into MFMA B-fragment layout ----------------
__global__ void pack_w1(const float* __restrict__ Wih, const float* __restrict__ Whh,
                        unsigned short* __restrict__ Bp) {
    int idx = blockIdx.x * blockDim.x + threadIdx.x;
    if (idx >= 2 * 64 * 9 * 64) return;
    int fl   = idx / (64 * 9 * 64);
    int rem  = idx % (64 * 9 * 64);
    int tile = rem / (9 * 64);
    int kk   = (rem / 64) % 9;
    int l    = rem & 63;
    int n    = tile * 16 + (l & 15);
    int k0   = kk * 32 + (l >> 4) * 8;
    unsigned short* dst = Bp + (size_t)idx * 8;
#pragma unroll
    for (int j = 0; j < 8; ++j) {
        int k = k0 + j;
        float v = (k < NH) ? Whh[((size_t)fl * G4 + n) * NH + k]
                           : Wih[((size_t)fl * G4 + n) * NIN + (k - NH)];
        dst[j] = f2bf(v);
    }
}

__global__ void pack_w2(const float* __restrict__ Wih, const float* __restrict__ Whh,
                        unsigned short* __restrict__ Bp) {
    int idx = blockIdx.x * blockDim.x + threadIdx.x;
    if (idx >= 64 * 16 * 64) return;
    int tile = idx / (16 * 64);
    int kk   = (idx / 64) % 16;
    int l    = idx & 63;
    int n    = tile * 16 + (l & 15);
    int k0   = kk * 32 + (l >> 4) * 8;
    unsigned short* dst = Bp + (size_t)idx * 8;
#pragma unroll
    for (int j = 0; j < 8; ++j) {
        int k = k0 + j;
        float v = (k < NH) ? Whh[(size_t)n * NH + k] : Wih[(size_t)n * NH + (k - NH)];
        dst[j] = f2bf(v);
    }
}

// ---------------- Layer 1 ----------------
// Grid 64: bid = j*16 + grp. Group grp (4 blocks j=0..3, same XCD since bid%8=grp%8)
// runs seqs sA=2*grp, sB=2*grp+1, phase-interleaved. Block j owns hidden cols
// j*64..j*64+63. Wave w (8 waves): cg=w&3, g0=w>>2 -> tiles (g0,cg),(g0+2,cg);
// weights for BOTH flag variants resident in VGPRs (36 bf16x8 = 144 VGPR).
// Exchange: tagged uint {bf16<<16|t+1}, relaxed AGENT atomics, parity double-buffer.
#define STRA 320                 // A_sh row stride in ushorts; 640B = 5*128B -> XOR-safe
#define ASH_BYTES (NB * STRA * 2)  // 10240 per buffer

__device__ __forceinline__ unsigned aoff(int row, int col) {  // byte offset, swizzled
    return (((unsigned)(row * STRA + col)) * 2u) ^ (((unsigned)row & 7u) << 4);
}

__device__ __forceinline__ void l1_phase(
    int t, int s_this,
    unsigned char* AshCur, unsigned char* AshOth,
    const bf16x8 (&W)[2][9], float b0, float b1, float (&cst)[2],
    ull* hx_this, const ull* hx_oth, int tag_oth,
    const float* __restrict__ x, unsigned short* __restrict__ h1bf,
    float (&gate)[4][64][17],
    int j, int lr, int kg, int cg, int g0,
    int pb, int c0, int rc)
{
    // 1. issue remote-h loads for the OTHER sequence (consumed at step 5)
    ull rv0 = 0, rv1 = 0, rv2 = 0, rv3 = 0;
    const ull* osrc = hx_oth + ((size_t)(tag_oth & 1) * NB + pb) * 128 + (rc >> 1);
    if (tag_oth > 0) {
        rv0 = __hip_atomic_load(osrc + 0, __ATOMIC_RELAXED, __HIP_MEMORY_SCOPE_AGENT);
        rv1 = __hip_atomic_load(osrc + 1, __ATOMIC_RELAXED, __HIP_MEMORY_SCOPE_AGENT);
        rv2 = __hip_atomic_load(osrc + 2, __ATOMIC_RELAXED, __HIP_MEMORY_SCOPE_AGENT);
        rv3 = __hip_atomic_load(osrc + 3, __ATOMIC_RELAXED, __HIP_MEMORY_SCOPE_AGENT);
    }
    // 1b. x prefetch for this seq, step t+1 (pb=batch 0..15, c0/2+... -> use pb,xk below)
    const int xk = (c0 >> 1);  // 0..31
    float xpre = 0.f;
    if (t + 1 < SEQLEN)
        xpre = x[(((size_t)s_this * SEQLEN + t + 1) * NB + pb) * NIN + xk];

    // 2. MFMA: gates for tiles (g0,cg) and (g0+2,cg)
    f32x4 acc0 = {b0, b0, b0, b0}, acc1 = {b1, b1, b1, b1};
#pragma unroll
    for (int kk = 0; kk < 9; ++kk) {
        bf16x8 a = *(const bf16x8*)(AshCur + aoff(lr, kk * 32 + kg * 8));
        acc0 = __builtin_amdgcn_mfma_f32_16x16x32_bf16(a, W[0][kk], acc0, 0, 0, 0);
        acc1 = __builtin_amdgcn_mfma_f32_16x16x32_bf16(a, W[1][kk], acc1, 0, 0, 0);
    }
#pragma unroll
    for (int r = 0; r < 4; ++r) {
        gate[g0    ][cg * 16 + lr][kg * 4 + r] = acc0[r];
        gate[g0 + 2][cg * 16 + lr][kg * 4 + r] = acc1[r];
    }
    __syncthreads();  // B1: gates ready, all AshCur reads done

    // 3. epilogue: thread owns (batch pb, local cols c0,c0+1); post own slice early
    unsigned hw0, hw1;
    {
        float ig = gate[0][c0][pb], fg = gate[1][c0][pb];
        float gg = gate[2][c0][pb], og = gate[3][c0][pb];
        float cn = sigf(fg) * cst[0] + sigf(ig) * tanhfast(gg);
        cst[0] = cn;
        hw0 = ((unsigned)f2bf(sigf(og) * tanhfast(cn)) << 16) | (unsigned)(t + 1);
    }
    {
        float ig = gate[0][c0 + 1][pb], fg = gate[1][c0 + 1][pb];
        float gg = gate[2][c0 + 1][pb], og = gate[3][c0 + 1][pb];
        float cn = sigf(fg) * cst[1] + sigf(ig) * tanhfast(gg);
        cst[1] = cn;
        hw1 = ((unsigned)f2bf(sigf(og) * tanhfast(cn)) << 16) | (unsigned)(t + 1);
    }
    ushort2 own;
    own.x = (unsigned short)(hw0 >> 16);
    own.y = (unsigned short)(hw1 >> 16);
    *(ushort2*)(AshCur + aoff(pb, j * 64 + c0)) = own;
    if (t == SEQLEN - 1) {
        *(ushort2*)&h1bf[((size_t)s_this * NB + pb) * NH + j * 64 + c0] = own;
    } else {
        ull pv = ((ull)hw1 << 32) | (ull)hw0;
        __hip_atomic_store(hx_this + ((size_t)((t + 1) & 1) * NB + pb) * 128 + ((j * 64 + c0) >> 1),
                           pv, __ATOMIC_RELAXED, __HIP_MEMORY_SCOPE_AGENT);
    }
    // 4. x(t+1) -> AshCur
    if (t + 1 < SEQLEN)
        *(unsigned short*)(AshCur + aoff(pb, NH + xk)) = f2bf(xpre);

    // 5. complete AshOth with remote h (tag-check + rare retry)
    if (tag_oth > 0) {
        const unsigned tg = (unsigned)tag_oth;
        while (((unsigned)(rv0 & 0xFFFFu) != tg) || ((unsigned)((rv0 >> 32) & 0xFFFFu) != tg))
            rv0 = __hip_atomic_load(osrc + 0, __ATOMIC_RELAXED, __HIP_MEMORY_SCOPE_AGENT);
        while (((unsigned)(rv1 & 0xFFFFu) != tg) || ((unsigned)((rv1 >> 32) & 0xFFFFu) != tg))
            rv1 = __hip_atomic_load(osrc + 1, __ATOMIC_RELAXED, __HIP_MEMORY_SCOPE_AGENT);
        while (((unsigned)(rv2 & 0xFFFFu) != tg) || ((unsigned)((rv2 >> 32) & 0xFFFFu) != tg))
            rv2 = __hip_atomic_load(osrc + 2, __ATOMIC_RELAXED, __HIP_MEMORY_SCOPE_AGENT);
        while (((unsigned)(rv3 & 0xFFFFu) != tg) || ((unsigned)((rv3 >> 32) & 0xFFFFu) != tg))
            rv3 = __hip_atomic_load(osrc + 3, __ATOMIC_RELAXED, __HIP_MEMORY_SCOPE_AGENT);
        ushort4 w0, w1;
        w0.x = (unsigned short)(rv0 >> 16); w0.y = (unsigned short)(rv0 >> 48);
        w0.z = (unsigned short)(rv1 >> 16); w0.w = (unsigned short)(rv1 >> 48);
        w1.x = (unsigned short)(rv2 >> 16); w1.y = (unsigned short)(rv2 >> 48);
        w1.z = (unsigned short)(rv3 >> 16); w1.w = (unsigned short)(rv3 >> 48);
        unsigned char* dst = AshOth + aoff(pb, rc);
        *(ushort4*)dst = w0;
        *(ushort4*)(dst + 8) = w1;
    }
    __syncthreads();  // B2
}

__global__ __launch_bounds__(512, 2) void lstm_layer1(
    const float* __restrict__ x, const int* __restrict__ flags,
    const float* __restrict__ bih, const float* __restrict__ bhh,
    const unsigned short* __restrict__ Bp_all,
    unsigned short* __restrict__ h1bf,
    ull* __restrict__ hx)     // [NSEQ][2][NB][128] ull
{
    __shared__ __align__(16) unsigned char Ash[2][ASH_BYTES];  // per seq: [h(256)|x(32)] swizzled
    __shared__ float gate[4][64][17];

    const int bid = blockIdx.x;
    const int grp = bid & 15, j = bid >> 4;
    const int sA = grp * 2, sB = sA + 1;
    const int tid = threadIdx.x;
    const int w = tid >> 6, l = tid & 63, lr = l & 15, kg = l >> 4;
    const int cg = w & 3, g0 = w >> 2;
    const int T0 = g0 * 16 + j * 4 + cg, T1 = (g0 + 2) * 16 + j * 4 + cg;
    const int flA = flags[sA], flB = flags[sB];

    bf16x8 WA[2][9], WB[2][9];
    const unsigned short* BpA = Bp_all + (size_t)flA * (64 * 9 * 64 * 8);
    const unsigned short* BpB = Bp_all + (size_t)flB * (64 * 9 * 64 * 8);
#pragma unroll
    for (int kk = 0; kk < 9; ++kk) {
        WA[0][kk] = *(const bf16x8*)(BpA + ((size_t)(T0 * 9 + kk) * 64 + l) * 8);
        WA[1][kk] = *(const bf16x8*)(BpA + ((size_t)(T1 * 9 + kk) * 64 + l) * 8);
        WB[0][kk] = *(const bf16x8*)(BpB + ((size_t)(T0 * 9 + kk) * 64 + l) * 8);
        WB[1][kk] = *(const bf16x8*)(BpB + ((size_t)(T1 * 9 + kk) * 64 + l) * 8);
    }
    const float bA0 = bih[flA * G4 + T0 * 16 + lr] + bhh[flA * G4 + T0 * 16 + lr];
    const float bA1 = bih[flA * G4 + T1 * 16 + lr] + bhh[flA * G4 + T1 * 16 + lr];
    const float bB0 = bih[flB * G4 + T0 * 16 + lr] + bhh[flB * G4 + T0 * 16 + lr];
    const float bB1 = bih[flB * G4 + T1 * 16 + lr] + bhh[flB * G4 + T1 * 16 + lr];

    const int pb = tid >> 5;           // batch 0..15
    const int pm = tid & 31;
    const int c0 = pm * 2;             // epilogue local col pair
    const int rc = pm * 8;             // readback col group (8 cols)

    float cstA[2] = {0.f, 0.f}, cstB[2] = {0.f, 0.f};

    ull* hxA = hx + (size_t)sA * 4096;   // per-seq: 2*16*128 ull
    ull* hxB = hx + (size_t)sB * 4096;

    // init: zero both A_sh buffers, then x(0) for both seqs
    for (int i = tid * 4; i < 2 * ASH_BYTES; i += 512 * 4)
        *(unsigned*)(&Ash[0][0] + i) = 0u;
    __syncthreads();
    {
        const int xk = pm;
        *(unsigned short*)(&Ash[0][0] + aoff(pb, NH + xk)) =
            f2bf(x[(((size_t)sA * SEQLEN) * NB + pb) * NIN + xk]);
        *(unsigned short*)(&Ash[1][0] + aoff(pb, NH + xk)) =
            f2bf(x[(((size_t)sB * SEQLEN) * NB + pb) * NIN + xk]);
    }
    __syncthreads();

    for (int t = 0; t < SEQLEN; ++t) {
        // phase A: compute seq A step t; complete A_sh[B] with h_B(t) (skip t=0: zeros)
        l1_phase(t, sA, &Ash[0][0], &Ash[1][0], WA, bA0, bA1, cstA,
                 hxA, hxB, t, x, h1bf, gate, j, lr, kg, cg, g0, pb, c0, rc);
        // phase B: compute seq B step t; complete A_sh[A] with h_A(t+1) (skip last)
        l1_phase(t, sB, &Ash[1][0], &Ash[0][0], WB, bB0, bB1, cstB,
                 hxB, hxA, (t + 1 < SEQLEN) ? (t + 1) : 0, x, h1bf, gate,
                 j, lr, kg, cg, g0, pb, c0, rc);
    }
}

// ---------------- Layer 2: 4 blocks, 32-step scan, tagged exchange ----------------
#define STRA2 520  // 512 data + 8 pad

__global__ __launch_bounds__(1024, 4) void lstm_layer2(
    const unsigned short* __restrict__ h1bf,
    const float* __restrict__ bih2, const float* __restrict__ bhh2,
    const unsigned short* __restrict__ Bp2,
    const float* __restrict__ Wlin, const float* __restrict__ blin,
    float* __restrict__ out,
    ull* __restrict__ hx2)     // [2][NB][128] ull
{
    const int j = blockIdx.x;  // 0..3

    __shared__ __align__(16) unsigned short A_sh[NB * STRA2];  // [h2(256)|h1_s(256)]
    __shared__ float gate[4][64][17];
    __shared__ float red[NB * 16];

    const int tid = threadIdx.x;
    const int w = tid >> 6, l = tid & 63, lr = l & 15, kg = l >> 4;
    const int g = w >> 2, cg = w & 3;
    const int tile = g * 16 + j * 4 + cg;

    bf16x8 wreg[16];
#pragma unroll
    for (int kk = 0; kk < 16; ++kk)
        wreg[kk] = *(const bf16x8*)(Bp2 + ((size_t)(tile * 16 + kk) * 64 + l) * 8);

    const int grow = tile * 16 + lr;
    const float bias = bih2[grow] + bhh2[grow];
    const int pb = tid >> 6, pc = tid & 63;          // epilogue: 1 col per thread
    float cst = 0.f;
    const int rb = tid >> 6, rc4 = (tid & 63) * 4;   // readback: 4 cols per thread

    for (int i = tid; i < NB * NH; i += 1024)
        A_sh[(i >> 8) * STRA2 + (i & 255)] = 0;
    *(ushort4*)&A_sh[rb * STRA2 + NH + rc4] = *(const ushort4*)&h1bf[(size_t)rb * NH + rc4];
    __syncthreads();

    for (int sq = 0; sq < NSEQ; ++sq) {
        ushort4 pre = {0, 0, 0, 0};
        if (sq + 1 < NSEQ)
            pre = *(const ushort4*)&h1bf[((size_t)(sq + 1) * NB + rb) * NH + rc4];

        f32x4 acc = {bias, bias, bias, bias};
#pragma unroll
        for (int kk = 0; kk < 16; ++kk) {
            bf16x8 a = *(const bf16x8*)&A_sh[lr * STRA2 + kk * 32 + kg * 8];
            acc = __builtin_amdgcn_mfma_f32_16x16x32_bf16(a, wreg[kk], acc, 0, 0, 0);
        }
#pragma unroll
        for (int r = 0; r < 4; ++r)
            gate[g][cg * 16 + lr][kg * 4 + r] = acc[r];
        __syncthreads();  // B1

        // epilogue + early post
        {
            float ig = gate[0][pc][pb], fg = gate[1][pc][pb];
            float gg = gate[2][pc][pb], og = gate[3][pc][pb];
            float cn = sigf(fg) * cst + sigf(ig) * tanhfast(gg);
            cst = cn;
            float h = sigf(og) * tanhfast(cn);
            unsigned hw = ((unsigned)f2bf(h) << 16) | (unsigned)(sq + 1);
            A_sh[pb * STRA2 + j * 64 + pc] = (unsigned short)(hw >> 16);
            __hip_atomic_store((unsigned*)hx2 + (((size_t)((sq + 1) & 1) * NB + pb) << 8) + j * 64 + pc,
                               hw, __ATOMIC_RELAXED, __HIP_MEMORY_SCOPE_AGENT);
        }
        if (sq + 1 < NSEQ)
            *(ushort4*)&A_sh[rb * STRA2 + NH + rc4] = pre;

        // readback h2(sq+1)
        {
            const ull* src = hx2 + (((size_t)((sq + 1) & 1) * NB + rb) << 7) + (rc4 >> 1);
            ull v0 = __hip_atomic_load(src + 0, __ATOMIC_RELAXED, __HIP_MEMORY_SCOPE_AGENT);
            ull v1 = __hip_atomic_load(src + 1, __ATOMIC_RELAXED, __HIP_MEMORY_SCOPE_AGENT);
            const unsigned tg = (unsigned)(sq + 1);
            while (((unsigned)(v0 & 0xFFFFu) != tg) || ((unsigned)((v0 >> 32) & 0xFFFFu) != tg))
                v0 = __hip_atomic_load(src + 0, __ATOMIC_RELAXED, __HIP_MEMORY_SCOPE_AGENT);
            while (((unsigned)(v1 & 0xFFFFu) != tg) || ((unsigned)((v1 >> 32) & 0xFFFFu) != tg))
                v1 = __hip_atomic_load(src + 1, __ATOMIC_RELAXED, __HIP_MEMORY_SCOPE_AGENT);
            ushort4 wv;
            wv.x = (unsigned short)(v0 >> 16); wv.y = (unsigned short)(v0 >> 48);
            wv.z = (unsigned short)(v1 >> 16); wv.w = (unsigned short)(v1 >> 48);
            *(ushort4*)&A_sh[rb * STRA2 + rc4] = wv;
        }
        __syncthreads();  // B2
    }

    // final linear + sigmoid, block 0 (A_sh h-part holds full final h2)
    if (j == 0) {
        if (tid < 256) {
            int b = tid >> 4, kc = tid & 15;
            float pacc = 0.f;
#pragma unroll
            for (int k = 0; k < 16; ++k)
                pacc += bf2f(A_sh[b * STRA2 + kc * 16 + k]) * Wlin[kc * 16 + k];
            red[b * 16 + kc] = pacc;
        }
        __syncthreads();
        if (tid < 16) {
            float ssum = blin[0];
#pragma unroll
            for (int kc = 0; kc < 16; ++kc) ssum += red[tid * 16 + kc];
            out[tid] = 1.0f / (1.0f + __expf(-ssum));
        }
    }
}

// ---------------- host ----------------
extern "C" void kernel_launch(void* const* d_in, const int* in_sizes, int n_in,
                              void* d_out, int out_size, void* d_ws, size_t ws_size,
                              hipStream_t stream) {
    const float* x    = (const float*)d_in[0];
    const int*   flg  = (const int*)d_in[1];
    const float* Wih1 = (const float*)d_in[2];
    const float* Whh1 = (const float*)d_in[3];
    const float* bih1 = (const float*)d_in[4];
    const float* bhh1 = (const float*)d_in[5];
    const float* Wih2 = (const float*)d_in[6];
    const float* Whh2 = (const float*)d_in[7];
    const float* bih2 = (const float*)d_in[8];
    const float* bhh2 = (const float*)d_in[9];
    const float* Wlin = (const float*)d_in[10];
    const float* blin = (const float*)d_in[11];
    float* out = (float*)d_out;

    // workspace layout (ushort units; ull regions 8B-aligned)
    unsigned short* ws   = (unsigned short*)d_ws;
    unsigned short* Bp1  = ws;                     // 2*64*9*64*8  = 589824 ush
    unsigned short* Bp2  = Bp1 + 589824;           // 64*16*64*8   = 524288 ush
    unsigned short* h1bf = Bp2 + 524288;           // 32*16*256    = 131072 ush
    ull*            hx1  = (ull*)(h1bf + 131072);  // 32*2*16*128  = 131072 ull
    ull*            hx2  = hx1 + 131072;           // 2*16*128     = 4096 ull
    // total: 1245184 ush + 135168 ull = ~3.57 MB

    // invalidate all exchange tags for this launch (graph-capture-safe)
    hipMemsetAsync(hx1, 0, (131072 + 4096) * sizeof(ull), stream);

    pack_w1<<<dim3(288), dim3(256), 0, stream>>>(Wih1, Whh1, Bp1);
    pack_w2<<<dim3(256), dim3(256), 0, stream>>>(Wih2, Whh2, Bp2);
    lstm_layer1<<<dim3(64), dim3(512), 0, stream>>>(x, flg, bih1, bhh1, Bp1, h1bf, hx1);
    lstm_layer2<<<dim3(4), dim3(1024), 0, stream>>>(h1bf, bih2, bhh2, Bp2, Wlin, blin, out, hx2);
}

// Round 5
// 677.237 us; speedup vs baseline: 1.7118x; 1.7118x over previous
//
#include <hip/hip_runtime.h>
#include <hip/hip_bf16.h>

// Sizes from the reference
#define NSEQ   32
#define SEQLEN 256
#define NB     16    // batch
#define NIN    32
#define NH     256
#define G4     1024  // 4*H

typedef __attribute__((ext_vector_type(8))) short bf16x8;
typedef __attribute__((ext_vector_type(4))) float f32x4;
typedef unsigned long long ull;

__device__ __forceinline__ unsigned short f2bf(float f) {
    union { float f; unsigned u; } v; v.f = f;
    unsigned u = v.u;
    return (unsigned short)((u + 0x7FFFu + ((u >> 16) & 1u)) >> 16);  // RNE
}
__device__ __forceinline__ float bf2f(unsigned short u) {
    union { unsigned u; float f; } v; v.u = ((unsigned)u) << 16; return v.f;
}
__device__ __forceinline__ float sigf(float x) { return 1.0f / (1.0f + __expf(-x)); }
__device__ __forceinline__ float tanhfast(float x) { return 1.0f - 2.0f / (__expf(2.0f * x) + 1.0f); }

// ---------------- Prologue: pack weights into MFMA B-fragment layout ----------------
__global__ void pack_w1(const float* __restrict__ Wih, const float* __restrict__ Whh,
                        unsigned short* __restrict__ Bp) {
    int idx = blockIdx.x * blockDim.x + threadIdx.x;
    if (idx >= 2 * 64 * 9 * 64) return;
    int fl   = idx / (64 * 9 * 64);
    int rem  = idx % (64 * 9 * 64);
    int tile = rem / (9 * 64);
    int kk   = (rem / 64) % 9;
    int l    = rem & 63;
    int n    = tile * 16 + (l & 15);
    int k0   = kk * 32 + (l >> 4) * 8;
    unsigned short* dst = Bp + (size_t)idx * 8;
#pragma unroll
    for (int j = 0; j < 8; ++j) {
        int k = k0 + j;
        float v = (k < NH) ? Whh[((size_t)fl * G4 + n) * NH + k]
                           : Wih[((size_t)fl * G4 + n) * NIN + (k - NH)];
        dst[j] = f2bf(v);
    }
}

__global__ void pack_w2(const float* __restrict__ Wih, const float* __restrict__ Whh,
                        unsigned short* __restrict__ Bp) {
    int idx = blockIdx.x * blockDim.x + threadIdx.x;
    if (idx >= 64 * 16 * 64) return;
    int tile = idx / (16 * 64);
    int kk   = (idx / 64) % 16;
    int l    = idx & 63;
    int n    = tile * 16 + (l & 15);
    int k0   = kk * 32 + (l >> 4) * 8;
    unsigned short* dst = Bp + (size_t)idx * 8;
#pragma unroll
    for (int j = 0; j < 8; ++j) {
        int k = k0 + j;
        float v = (k < NH) ? Whh[(size_t)n * NH + k] : Wih[(size_t)n * NH + (k - NH)];
        dst[j] = f2bf(v);
    }
}

// ---------------- Layer 1: 4 blocks/seq, weights in regs, tagged-data sync ----------------
// bid = j*32 + s (4 blocks of seq s land on XCD s%8). Block (s,j) owns cols
// j*64..j*64+63. Wave w of 16: gate g=w>>2, colgroup cg=w&3, tile=g*16+j*4+cg,
// its 9 K-fragments resident in VGPRs (36 VGPR).
// Exchange: tagged uint {bf16(h)<<16 | (t+1)}, relaxed AGENT atomics, parity
// double-buffer. Safety: read(gen t) ->po post(gen t+1) ->rf peer read-success
// ->po peer post(gen t+2) -- overwrite always happens-after all reads.
#define STRA 320                   // Ash row stride in ushorts; 640B = 5*128B
#define ASH_BYTES (NB * STRA * 2)  // 10240

__device__ __forceinline__ unsigned aoff(int row, int col) {  // swizzled byte offset
    return (((unsigned)(row * STRA + col)) * 2u) ^ (((unsigned)row & 7u) << 4);
}

__global__ __launch_bounds__(1024) void lstm_layer1(
    const float* __restrict__ x, const int* __restrict__ flags,
    const float* __restrict__ bih, const float* __restrict__ bhh,
    const unsigned short* __restrict__ Bp_all,
    unsigned short* __restrict__ h1bf,
    unsigned* __restrict__ hxu)    // [NSEQ][2][NB][256] tagged uints
{
    __shared__ __align__(16) unsigned char Ash[ASH_BYTES];  // [h(256)|x(32)] swizzled
    __shared__ float gate[4][64][17];

    const int bid = blockIdx.x;
    const int s   = bid & 31;
    const int j   = bid >> 5;
    const int tid = threadIdx.x;
    const int w = tid >> 6, l = tid & 63, lr = l & 15, kg = l >> 4;
    const int g = w >> 2, cg = w & 3;
    const int fl = flags[s];
    const int tile = g * 16 + j * 4 + cg;
    const unsigned short* Bp = Bp_all + (size_t)fl * (64 * 9 * 64 * 8);

    bf16x8 wreg[9];
#pragma unroll
    for (int kk = 0; kk < 9; ++kk)
        wreg[kk] = *(const bf16x8*)(Bp + ((size_t)(tile * 9 + kk) * 64 + l) * 8);

    const int grow = tile * 16 + lr;
    const float bias = bih[fl * G4 + grow] + bhh[fl * G4 + grow];

    const int pb = tid >> 6, pc = tid & 63;   // epilogue/post/readback: (batch, local col)
    const int o0 = (((j + 1) & 3) << 6) + pc; // the 3 peer column slots
    const int o1 = (((j + 2) & 3) << 6) + pc;
    const int o2 = (((j + 3) & 3) << 6) + pc;
    const int xb = tid >> 5, xk = tid & 31;   // x staging (tid < 512)
    float cst = 0.f;

    unsigned* hxseq = hxu + (size_t)s * (2 * NB * 256);

    for (int i = tid * 4; i < ASH_BYTES; i += 1024 * 4)
        *(unsigned*)(Ash + i) = 0u;
    __syncthreads();
    if (tid < NB * NIN)
        *(unsigned short*)(Ash + aoff(xb, NH + xk)) =
            f2bf(x[(((size_t)s * SEQLEN) * NB + xb) * NIN + xk]);
    __syncthreads();

    for (int t = 0; t < SEQLEN; ++t) {
        float xpre = 0.f;
        if (t + 1 < SEQLEN && tid < NB * NIN)
            xpre = x[(((size_t)s * SEQLEN + t + 1) * NB + xb) * NIN + xk];

        f32x4 acc = {bias, bias, bias, bias};
#pragma unroll
        for (int kk = 0; kk < 9; ++kk) {
            bf16x8 a = *(const bf16x8*)(Ash + aoff(lr, kk * 32 + kg * 8));
            acc = __builtin_amdgcn_mfma_f32_16x16x32_bf16(a, wreg[kk], acc, 0, 0, 0);
        }
#pragma unroll
        for (int r = 0; r < 4; ++r)
            gate[g][cg * 16 + lr][kg * 4 + r] = acc[r];
        __syncthreads();  // B1: gates ready, all Ash reads of step t done

        // epilogue: 1 thread = 1 (batch, col)
        float ig = gate[0][pc][pb], fg = gate[1][pc][pb];
        float gg = gate[2][pc][pb], og = gate[3][pc][pb];
        float cn = sigf(fg) * cst + sigf(ig) * tanhfast(gg);
        cst = cn;
        float h = sigf(og) * tanhfast(cn);
        unsigned short hb = f2bf(h);
        *(unsigned short*)(Ash + aoff(pb, (j << 6) + pc)) = hb;  // own col -> LDS

        if (t == SEQLEN - 1) {
            h1bf[((size_t)s * NB + pb) * NH + (j << 6) + pc] = hb;
        } else {
            const unsigned tg = (unsigned)(t + 1);
            unsigned* row = hxseq + ((((t + 1) & 1) * NB + pb) << 8);
            __hip_atomic_store(row + (j << 6) + pc, ((unsigned)hb << 16) | tg,
                               __ATOMIC_RELAXED, __HIP_MEMORY_SCOPE_AGENT);
            // x(t+1) -> Ash while posts/loads are in flight
            if (tid < NB * NIN)
                *(unsigned short*)(Ash + aoff(xb, NH + xk)) = f2bf(xpre);
            // readback: 3 peer cols, tag-checked (readback load IS the sync)
            unsigned v0 = __hip_atomic_load(row + o0, __ATOMIC_RELAXED, __HIP_MEMORY_SCOPE_AGENT);
            unsigned v1 = __hip_atomic_load(row + o1, __ATOMIC_RELAXED, __HIP_MEMORY_SCOPE_AGENT);
            unsigned v2 = __hip_atomic_load(row + o2, __ATOMIC_RELAXED, __HIP_MEMORY_SCOPE_AGENT);
            while ((v0 & 0xFFFFu) != tg)
                v0 = __hip_atomic_load(row + o0, __ATOMIC_RELAXED, __HIP_MEMORY_SCOPE_AGENT);
            while ((v1 & 0xFFFFu) != tg)
                v1 = __hip_atomic_load(row + o1, __ATOMIC_RELAXED, __HIP_MEMORY_SCOPE_AGENT);
            while ((v2 & 0xFFFFu) != tg)
                v2 = __hip_atomic_load(row + o2, __ATOMIC_RELAXED, __HIP_MEMORY_SCOPE_AGENT);
            *(unsigned short*)(Ash + aoff(pb, o0)) = (unsigned short)(v0 >> 16);
            *(unsigned short*)(Ash + aoff(pb, o1)) = (unsigned short)(v1 >> 16);
            *(unsigned short*)(Ash + aoff(pb, o2)) = (unsigned short)(v2 >> 16);
            __syncthreads();  // B2: Ash complete for step t+1
        }
    }
}

// ---------------- Layer 2: 4 blocks, 32-step scan, tagged exchange ----------------
#define STRA2 520  // 512 data + 8 pad

__global__ __launch_bounds__(1024, 4) void lstm_layer2(
    const unsigned short* __restrict__ h1bf,
    const float* __restrict__ bih2, const float* __restrict__ bhh2,
    const unsigned short* __restrict__ Bp2,
    const float* __restrict__ Wlin, const float* __restrict__ blin,
    float* __restrict__ out,
    ull* __restrict__ hx2)     // [2][NB][128] ull viewed as tagged uints
{
    const int j = blockIdx.x;  // 0..3

    __shared__ __align__(16) unsigned short A_sh[NB * STRA2];  // [h2(256)|h1_s(256)]
    __shared__ float gate[4][64][17];
    __shared__ float red[NB * 16];

    const int tid = threadIdx.x;
    const int w = tid >> 6, l = tid & 63, lr = l & 15, kg = l >> 4;
    const int g = w >> 2, cg = w & 3;
    const int tile = g * 16 + j * 4 + cg;

    bf16x8 wreg[16];
#pragma unroll
    for (int kk = 0; kk < 16; ++kk)
        wreg[kk] = *(const bf16x8*)(Bp2 + ((size_t)(tile * 16 + kk) * 64 + l) * 8);

    const int grow = tile * 16 + lr;
    const float bias = bih2[grow] + bhh2[grow];
    const int pb = tid >> 6, pc = tid & 63;          // epilogue: 1 col per thread
    float cst = 0.f;
    const int rb = tid >> 6, rc4 = (tid & 63) * 4;   // h1 staging: 4 cols per thread

    for (int i = tid; i < NB * NH; i += 1024)
        A_sh[(i >> 8) * STRA2 + (i & 255)] = 0;
    *(ushort4*)&A_sh[rb * STRA2 + NH + rc4] = *(const ushort4*)&h1bf[(size_t)rb * NH + rc4];
    __syncthreads();

    for (int sq = 0; sq < NSEQ; ++sq) {
        ushort4 pre = {0, 0, 0, 0};
        if (sq + 1 < NSEQ)
            pre = *(const ushort4*)&h1bf[((size_t)(sq + 1) * NB + rb) * NH + rc4];

        f32x4 acc = {bias, bias, bias, bias};
#pragma unroll
        for (int kk = 0; kk < 16; ++kk) {
            bf16x8 a = *(const bf16x8*)&A_sh[lr * STRA2 + kk * 32 + kg * 8];
            acc = __builtin_amdgcn_mfma_f32_16x16x32_bf16(a, wreg[kk], acc, 0, 0, 0);
        }
#pragma unroll
        for (int r = 0; r < 4; ++r)
            gate[g][cg * 16 + lr][kg * 4 + r] = acc[r];
        __syncthreads();  // B1

        // epilogue + early post
        {
            float ig = gate[0][pc][pb], fg = gate[1][pc][pb];
            float gg = gate[2][pc][pb], og = gate[3][pc][pb];
            float cn = sigf(fg) * cst + sigf(ig) * tanhfast(gg);
            cst = cn;
            float h = sigf(og) * tanhfast(cn);
            unsigned hw = ((unsigned)f2bf(h) << 16) | (unsigned)(sq + 1);
            A_sh[pb * STRA2 + (j << 6) + pc] = (unsigned short)(hw >> 16);
            __hip_atomic_store((unsigned*)hx2 + ((((sq + 1) & 1) * NB + pb) << 8) + (j << 6) + pc,
                               hw, __ATOMIC_RELAXED, __HIP_MEMORY_SCOPE_AGENT);
        }
        if (sq + 1 < NSEQ)
            *(ushort4*)&A_sh[rb * STRA2 + NH + rc4] = pre;

        // readback h2(sq+1): 3 peer cols per thread, tag-checked
        {
            const unsigned tg = (unsigned)(sq + 1);
            unsigned* row = (unsigned*)hx2 + ((((sq + 1) & 1) * NB + pb) << 8);
            const int q0 = (((j + 1) & 3) << 6) + pc;
            const int q1 = (((j + 2) & 3) << 6) + pc;
            const int q2 = (((j + 3) & 3) << 6) + pc;
            unsigned v0 = __hip_atomic_load(row + q0, __ATOMIC_RELAXED, __HIP_MEMORY_SCOPE_AGENT);
            unsigned v1 = __hip_atomic_load(row + q1, __ATOMIC_RELAXED, __HIP_MEMORY_SCOPE_AGENT);
            unsigned v2 = __hip_atomic_load(row + q2, __ATOMIC_RELAXED, __HIP_MEMORY_SCOPE_AGENT);
            while ((v0 & 0xFFFFu) != tg)
                v0 = __hip_atomic_load(row + q0, __ATOMIC_RELAXED, __HIP_MEMORY_SCOPE_AGENT);
            while ((v1 & 0xFFFFu) != tg)
                v1 = __hip_atomic_load(row + q1, __ATOMIC_RELAXED, __HIP_MEMORY_SCOPE_AGENT);
            while ((v2 & 0xFFFFu) != tg)
                v2 = __hip_atomic_load(row + q2, __ATOMIC_RELAXED, __HIP_MEMORY_SCOPE_AGENT);
            A_sh[pb * STRA2 + q0] = (unsigned short)(v0 >> 16);
            A_sh[pb * STRA2 + q1] = (unsigned short)(v1 >> 16);
            A_sh[pb * STRA2 + q2] = (unsigned short)(v2 >> 16);
        }
        __syncthreads();  // B2
    }

    // final linear + sigmoid, block 0 (A_sh h-part holds full final h2)
    if (j == 0) {
        if (tid < 256) {
            int b = tid >> 4, kc = tid & 15;
            float pacc = 0.f;
#pragma unroll
            for (int k = 0; k < 16; ++k)
                pacc += bf2f(A_sh[b * STRA2 + kc * 16 + k]) * Wlin[kc * 16 + k];
            red[b * 16 + kc] = pacc;
        }
        __syncthreads();
        if (tid < 16) {
            float ssum = blin[0];
#pragma unroll
            for (int kc = 0; kc < 16; ++kc) ssum += red[tid * 16 + kc];
            out[tid] = 1.0f / (1.0f + __expf(-ssum));
        }
    }
}

// ---------------- host ----------------
extern "C" void kernel_launch(void* const* d_in, const int* in_sizes, int n_in,
                              void* d_out, int out_size, void* d_ws, size_t ws_size,
                              hipStream_t stream) {
    const float* x    = (const float*)d_in[0];
    const int*   flg  = (const int*)d_in[1];
    const float* Wih1 = (const float*)d_in[2];
    const float* Whh1 = (const float*)d_in[3];
    const float* bih1 = (const float*)d_in[4];
    const float* bhh1 = (const float*)d_in[5];
    const float* Wih2 = (const float*)d_in[6];
    const float* Whh2 = (const float*)d_in[7];
    const float* bih2 = (const float*)d_in[8];
    const float* bhh2 = (const float*)d_in[9];
    const float* Wlin = (const float*)d_in[10];
    const float* blin = (const float*)d_in[11];
    float* out = (float*)d_out;

    // workspace layout (ushort units; later regions 8B-aligned)
    unsigned short* ws   = (unsigned short*)d_ws;
    unsigned short* Bp1  = ws;                       // 2*64*9*64*8  = 589824 ush
    unsigned short* Bp2  = Bp1 + 589824;             // 64*16*64*8   = 524288 ush
    unsigned short* h1bf = Bp2 + 524288;             // 32*16*256    = 131072 ush
    unsigned*       hxu1 = (unsigned*)(h1bf + 131072);  // 32*2*16*256 = 262144 uint
    ull*            hx2  = (ull*)(hxu1 + 262144);    // 2*16*128 ull = 32 KB
    // total ~= 3.5 MB

    // invalidate all exchange tags for this launch (captured in the graph)
    hipMemsetAsync(hxu1, 0, 262144 * 4 + 4096 * 8, stream);

    pack_w1<<<dim3(288), dim3(256), 0, stream>>>(Wih1, Whh1, Bp1);
    pack_w2<<<dim3(256), dim3(256), 0, stream>>>(Wih2, Whh2, Bp2);
    lstm_layer1<<<dim3(128), dim3(1024), 0, stream>>>(x, flg, bih1, bhh1, Bp1, h1bf, hxu1);
    lstm_layer2<<<dim3(4), dim3(1024), 0, stream>>>(h1bf, bih2, bhh2, Bp2, Wlin, blin, out, hx2);
}

// Round 6
// 625.895 us; speedup vs baseline: 1.8522x; 1.0820x over previous
//
#include <hip/hip_runtime.h>
#include <hip/hip_bf16.h>

// Sizes from the reference
#define NSEQ   32
#define SEQLEN 256
#define NB     16    // batch
#define NIN    32
#define NH     256
#define G4     1024  // 4*H

typedef __attribute__((ext_vector_type(8))) short bf16x8;
typedef __attribute__((ext_vector_type(4))) float f32x4;
typedef unsigned long long ull;

__device__ __forceinline__ unsigned short f2bf(float f) {
    union { float f; unsigned u; } v; v.f = f;
    unsigned u = v.u;
    return (unsigned short)((u + 0x7FFFu + ((u >> 16) & 1u)) >> 16);  // RNE
}
__device__ __forceinline__ float bf2f(unsigned short u) {
    union { unsigned u; float f; } v; v.u = ((unsigned)u) << 16; return v.f;
}
__device__ __forceinline__ float sigf(float x) { return 1.0f / (1.0f + __expf(-x)); }
__device__ __forceinline__ float tanhfast(float x) { return 1.0f - 2.0f / (__expf(2.0f * x) + 1.0f); }

// ---------------- Prologue: pack weights into MFMA B-fragment layout ----------------
__global__ void pack_w1(const float* __restrict__ Wih, const float* __restrict__ Whh,
                        unsigned short* __restrict__ Bp) {
    int idx = blockIdx.x * blockDim.x + threadIdx.x;
    if (idx >= 2 * 64 * 9 * 64) return;
    int fl   = idx / (64 * 9 * 64);
    int rem  = idx % (64 * 9 * 64);
    int tile = rem / (9 * 64);
    int kk   = (rem / 64) % 9;
    int l    = rem & 63;
    int n    = tile * 16 + (l & 15);
    int k0   = kk * 32 + (l >> 4) * 8;
    unsigned short* dst = Bp + (size_t)idx * 8;
#pragma unroll
    for (int j = 0; j < 8; ++j) {
        int k = k0 + j;
        float v = (k < NH) ? Whh[((size_t)fl * G4 + n) * NH + k]
                           : Wih[((size_t)fl * G4 + n) * NIN + (k - NH)];
        dst[j] = f2bf(v);
    }
}

__global__ void pack_w2(const float* __restrict__ Wih, const float* __restrict__ Whh,
                        unsigned short* __restrict__ Bp) {
    int idx = blockIdx.x * blockDim.x + threadIdx.x;
    if (idx >= 64 * 16 * 64) return;
    int tile = idx / (16 * 64);
    int kk   = (idx / 64) % 16;
    int l    = idx & 63;
    int n    = tile * 16 + (l & 15);
    int k0   = kk * 32 + (l >> 4) * 8;
    unsigned short* dst = Bp + (size_t)idx * 8;
#pragma unroll
    for (int j = 0; j < 8; ++j) {
        int k = k0 + j;
        float v = (k < NH) ? Whh[(size_t)n * NH + k] : Wih[(size_t)n * NH + (k - NH)];
        dst[j] = f2bf(v);
    }
}

// ---------------- Layer 1: 4 blocks/seq, dual-published tagged exchange ----------------
// bid = j*32 + s -> the 4 blocks of seq s share XCD s%8 (perf heuristic only).
// Exchange words {bf16(h)<<16 | (t+1)} are published BOTH to:
//   F: plain store -> shared same-XCD L2; read via volatile (sc0) loads, ~250cyc RT
//   S: relaxed AGENT atomic -> MALL; read via AGENT atomic loads, ~900cyc RT
// Readers probe F (bounded budget) and sticky-select F or S per thread.
// Correct under ANY block->XCD placement: F timeout always falls back to S.
#define STRA 320                   // Ash row stride in ushorts; 640B = 5*128B
#define ASH_BYTES (NB * STRA * 2)  // 10240

__device__ __forceinline__ unsigned aoff(int row, int col) {  // swizzled byte offset
    return (((unsigned)(row * STRA + col)) * 2u) ^ (((unsigned)row & 7u) << 4);
}

__global__ __launch_bounds__(1024) void lstm_layer1(
    const float* __restrict__ x, const int* __restrict__ flags,
    const float* __restrict__ bih, const float* __restrict__ bhh,
    const unsigned short* __restrict__ Bp_all,
    unsigned short* __restrict__ h1bf,
    unsigned* __restrict__ hxS,    // [NSEQ][2][NB][256] tagged uints (MALL path)
    unsigned* __restrict__ hxF)    // [NSEQ][2][NB][256] tagged uints (L2 path)
{
    __shared__ __align__(16) unsigned char Ash[ASH_BYTES];  // [h(256)|x(32)] swizzled
    __shared__ float gate[4][64][17];

    const int bid = blockIdx.x;
    const int s   = bid & 31;
    const int j   = bid >> 5;
    const int tid = threadIdx.x;
    const int w = tid >> 6, l = tid & 63, lr = l & 15, kg = l >> 4;
    const int g = w >> 2, cg = w & 3;
    const int fl = flags[s];
    const int tile = g * 16 + j * 4 + cg;
    const unsigned short* Bp = Bp_all + (size_t)fl * (64 * 9 * 64 * 8);

    bf16x8 wreg[9];
#pragma unroll
    for (int kk = 0; kk < 9; ++kk)
        wreg[kk] = *(const bf16x8*)(Bp + ((size_t)(tile * 9 + kk) * 64 + l) * 8);

    const int grow = tile * 16 + lr;
    const float bias = bih[fl * G4 + grow] + bhh[fl * G4 + grow];

    const int pb = tid >> 6, pc = tid & 63;   // epilogue/post/readback: (batch, local col)
    const int o0 = (((j + 1) & 3) << 6) + pc; // the 3 peer column slots
    const int o1 = (((j + 2) & 3) << 6) + pc;
    const int o2 = (((j + 3) & 3) << 6) + pc;
    const int xb = tid >> 5, xk = tid & 31;   // x staging (tid < 512)
    float cst = 0.f;
    int mode = 0;  // 0=probe, 1=fast(L2), 2=safe(MALL)

    unsigned* hxSs = hxS + (size_t)s * (2 * NB * 256);
    unsigned* hxFs = hxF + (size_t)s * (2 * NB * 256);

    for (int i = tid * 4; i < ASH_BYTES; i += 1024 * 4)
        *(unsigned*)(Ash + i) = 0u;
    __syncthreads();
    if (tid < NB * NIN)
        *(unsigned short*)(Ash + aoff(xb, NH + xk)) =
            f2bf(x[(((size_t)s * SEQLEN) * NB + xb) * NIN + xk]);
    __syncthreads();

    for (int t = 0; t < SEQLEN; ++t) {
        float xpre = 0.f;
        if (t + 1 < SEQLEN && tid < NB * NIN)
            xpre = x[(((size_t)s * SEQLEN + t + 1) * NB + xb) * NIN + xk];

        // MFMA: two independent 5/4-deep chains to shorten the dependency chain
        f32x4 acc = {bias, bias, bias, bias};
        f32x4 accB = {0.f, 0.f, 0.f, 0.f};
#pragma unroll
        for (int kk = 0; kk < 5; ++kk) {
            bf16x8 a = *(const bf16x8*)(Ash + aoff(lr, kk * 32 + kg * 8));
            acc = __builtin_amdgcn_mfma_f32_16x16x32_bf16(a, wreg[kk], acc, 0, 0, 0);
        }
#pragma unroll
        for (int kk = 5; kk < 9; ++kk) {
            bf16x8 a = *(const bf16x8*)(Ash + aoff(lr, kk * 32 + kg * 8));
            accB = __builtin_amdgcn_mfma_f32_16x16x32_bf16(a, wreg[kk], accB, 0, 0, 0);
        }
#pragma unroll
        for (int r = 0; r < 4; ++r)
            gate[g][cg * 16 + lr][kg * 4 + r] = acc[r] + accB[r];
        __syncthreads();  // B1: gates ready, all Ash reads of step t done

        // epilogue: 1 thread = 1 (batch, col)
        float ig = gate[0][pc][pb], fg = gate[1][pc][pb];
        float gg = gate[2][pc][pb], og = gate[3][pc][pb];
        float cn = sigf(fg) * cst + sigf(ig) * tanhfast(gg);
        cst = cn;
        float h = sigf(og) * tanhfast(cn);
        unsigned short hb = f2bf(h);
        *(unsigned short*)(Ash + aoff(pb, (j << 6) + pc)) = hb;  // own col -> LDS

        if (t == SEQLEN - 1) {
            h1bf[((size_t)s * NB + pb) * NH + (j << 6) + pc] = hb;
        } else {
            const unsigned tg = (unsigned)(t + 1);
            const unsigned word = ((unsigned)hb << 16) | tg;
            const size_t ro = (size_t)((((t + 1) & 1) * NB + pb) << 8);
            unsigned* rowF = hxFs + ro;
            unsigned* rowS = hxSs + ro;
            rowF[(j << 6) + pc] = word;  // fast publish: local-XCD L2
            __hip_atomic_store(rowS + (j << 6) + pc, word,
                               __ATOMIC_RELAXED, __HIP_MEMORY_SCOPE_AGENT);  // safe publish
            // x(t+1) -> Ash while posts are in flight
            if (tid < NB * NIN)
                *(unsigned short*)(Ash + aoff(xb, NH + xk)) = f2bf(xpre);

            // readback: 3 peer cols, tag-checked; sticky fast/safe selection
            unsigned v0, v1, v2;
            bool ok = false;
            if (mode != 2) {
                int budget = (mode == 0) ? 256 : 4000;
                volatile const unsigned* F = rowF;
                v0 = F[o0]; v1 = F[o1]; v2 = F[o2];
                while ((v0 & 0xFFFFu) != tg && budget-- > 0) v0 = F[o0];
                while ((v1 & 0xFFFFu) != tg && budget-- > 0) v1 = F[o1];
                while ((v2 & 0xFFFFu) != tg && budget-- > 0) v2 = F[o2];
                ok = ((v0 & 0xFFFFu) == tg) && ((v1 & 0xFFFFu) == tg) && ((v2 & 0xFFFFu) == tg);
                mode = ok ? 1 : 2;
            }
            if (!ok) {  // safe path: MALL, guaranteed to arrive
                v0 = __hip_atomic_load(rowS + o0, __ATOMIC_RELAXED, __HIP_MEMORY_SCOPE_AGENT);
                v1 = __hip_atomic_load(rowS + o1, __ATOMIC_RELAXED, __HIP_MEMORY_SCOPE_AGENT);
                v2 = __hip_atomic_load(rowS + o2, __ATOMIC_RELAXED, __HIP_MEMORY_SCOPE_AGENT);
                while ((v0 & 0xFFFFu) != tg)
                    v0 = __hip_atomic_load(rowS + o0, __ATOMIC_RELAXED, __HIP_MEMORY_SCOPE_AGENT);
                while ((v1 & 0xFFFFu) != tg)
                    v1 = __hip_atomic_load(rowS + o1, __ATOMIC_RELAXED, __HIP_MEMORY_SCOPE_AGENT);
                while ((v2 & 0xFFFFu) != tg)
                    v2 = __hip_atomic_load(rowS + o2, __ATOMIC_RELAXED, __HIP_MEMORY_SCOPE_AGENT);
            }
            *(unsigned short*)(Ash + aoff(pb, o0)) = (unsigned short)(v0 >> 16);
            *(unsigned short*)(Ash + aoff(pb, o1)) = (unsigned short)(v1 >> 16);
            *(unsigned short*)(Ash + aoff(pb, o2)) = (unsigned short)(v2 >> 16);
            __syncthreads();  // B2: Ash complete for step t+1
        }
    }
}

// ---------------- Layer 2: 4 blocks (grid 32, bid%8==0 -> same XCD), 32-step scan ----------------
#define STRA2 520  // 512 data + 8 pad

__global__ __launch_bounds__(1024) void lstm_layer2(
    const unsigned short* __restrict__ h1bf,
    const float* __restrict__ bih2, const float* __restrict__ bhh2,
    const unsigned short* __restrict__ Bp2,
    const float* __restrict__ Wlin, const float* __restrict__ blin,
    float* __restrict__ out,
    unsigned* __restrict__ hx2S,   // [2][NB][256] tagged uints (MALL)
    unsigned* __restrict__ hx2F)   // [2][NB][256] tagged uints (L2)
{
    const int bid = blockIdx.x;
    if (bid & 7) return;
    const int j = bid >> 3;  // 0..3

    __shared__ __align__(16) unsigned short A_sh[NB * STRA2];  // [h2(256)|h1_s(256)]
    __shared__ float gate[4][64][17];
    __shared__ float red[NB * 16];

    const int tid = threadIdx.x;
    const int w = tid >> 6, l = tid & 63, lr = l & 15, kg = l >> 4;
    const int g = w >> 2, cg = w & 3;
    const int tile = g * 16 + j * 4 + cg;

    bf16x8 wreg[16];
#pragma unroll
    for (int kk = 0; kk < 16; ++kk)
        wreg[kk] = *(const bf16x8*)(Bp2 + ((size_t)(tile * 16 + kk) * 64 + l) * 8);

    const int grow = tile * 16 + lr;
    const float bias = bih2[grow] + bhh2[grow];
    const int pb = tid >> 6, pc = tid & 63;          // epilogue: 1 col per thread
    float cst = 0.f;
    int mode = 0;
    const int rb = tid >> 6, rc4 = (tid & 63) * 4;   // h1 staging: 4 cols per thread
    const int q0 = (((j + 1) & 3) << 6) + pc;
    const int q1 = (((j + 2) & 3) << 6) + pc;
    const int q2 = (((j + 3) & 3) << 6) + pc;

    for (int i = tid; i < NB * NH; i += 1024)
        A_sh[(i >> 8) * STRA2 + (i & 255)] = 0;
    *(ushort4*)&A_sh[rb * STRA2 + NH + rc4] = *(const ushort4*)&h1bf[(size_t)rb * NH + rc4];
    __syncthreads();

    for (int sq = 0; sq < NSEQ; ++sq) {
        ushort4 pre = {0, 0, 0, 0};
        if (sq + 1 < NSEQ)
            pre = *(const ushort4*)&h1bf[((size_t)(sq + 1) * NB + rb) * NH + rc4];

        f32x4 acc = {bias, bias, bias, bias};
        f32x4 accB = {0.f, 0.f, 0.f, 0.f};
#pragma unroll
        for (int kk = 0; kk < 8; ++kk) {
            bf16x8 a = *(const bf16x8*)&A_sh[lr * STRA2 + kk * 32 + kg * 8];
            acc = __builtin_amdgcn_mfma_f32_16x16x32_bf16(a, wreg[kk], acc, 0, 0, 0);
        }
#pragma unroll
        for (int kk = 8; kk < 16; ++kk) {
            bf16x8 a = *(const bf16x8*)&A_sh[lr * STRA2 + kk * 32 + kg * 8];
            accB = __builtin_amdgcn_mfma_f32_16x16x32_bf16(a, wreg[kk], accB, 0, 0, 0);
        }
#pragma unroll
        for (int r = 0; r < 4; ++r)
            gate[g][cg * 16 + lr][kg * 4 + r] = acc[r] + accB[r];
        __syncthreads();  // B1

        // epilogue + dual publish
        const unsigned tg = (unsigned)(sq + 1);
        const size_t ro = (size_t)((((sq + 1) & 1) * NB + pb) << 8);
        unsigned* rowF = hx2F + ro;
        unsigned* rowS = hx2S + ro;
        {
            float ig = gate[0][pc][pb], fg = gate[1][pc][pb];
            float gg = gate[2][pc][pb], og = gate[3][pc][pb];
            float cn = sigf(fg) * cst + sigf(ig) * tanhfast(gg);
            cst = cn;
            float h = sigf(og) * tanhfast(cn);
            unsigned word = ((unsigned)f2bf(h) << 16) | tg;
            A_sh[pb * STRA2 + (j << 6) + pc] = (unsigned short)(word >> 16);
            rowF[(j << 6) + pc] = word;
            __hip_atomic_store(rowS + (j << 6) + pc, word,
                               __ATOMIC_RELAXED, __HIP_MEMORY_SCOPE_AGENT);
        }
        if (sq + 1 < NSEQ)
            *(ushort4*)&A_sh[rb * STRA2 + NH + rc4] = pre;

        // readback h2(sq+1): 3 peer cols, sticky fast/safe
        {
            unsigned v0, v1, v2;
            bool ok = false;
            if (mode != 2) {
                int budget = (mode == 0) ? 256 : 4000;
                volatile const unsigned* F = rowF;
                v0 = F[q0]; v1 = F[q1]; v2 = F[q2];
                while ((v0 & 0xFFFFu) != tg && budget-- > 0) v0 = F[q0];
                while ((v1 & 0xFFFFu) != tg && budget-- > 0) v1 = F[q1];
                while ((v2 & 0xFFFFu) != tg && budget-- > 0) v2 = F[q2];
                ok = ((v0 & 0xFFFFu) == tg) && ((v1 & 0xFFFFu) == tg) && ((v2 & 0xFFFFu) == tg);
                mode = ok ? 1 : 2;
            }
            if (!ok) {
                v0 = __hip_atomic_load(rowS + q0, __ATOMIC_RELAXED, __HIP_MEMORY_SCOPE_AGENT);
                v1 = __hip_atomic_load(rowS + q1, __ATOMIC_RELAXED, __HIP_MEMORY_SCOPE_AGENT);
                v2 = __hip_atomic_load(rowS + q2, __ATOMIC_RELAXED, __HIP_MEMORY_SCOPE_AGENT);
                while ((v0 & 0xFFFFu) != tg)
                    v0 = __hip_atomic_load(rowS + q0, __ATOMIC_RELAXED, __HIP_MEMORY_SCOPE_AGENT);
                while ((v1 & 0xFFFFu) != tg)
                    v1 = __hip_atomic_load(rowS + q1, __ATOMIC_RELAXED, __HIP_MEMORY_SCOPE_AGENT);
                while ((v2 & 0xFFFFu) != tg)
                    v2 = __hip_atomic_load(rowS + q2, __ATOMIC_RELAXED, __HIP_MEMORY_SCOPE_AGENT);
            }
            A_sh[pb * STRA2 + q0] = (unsigned short)(v0 >> 16);
            A_sh[pb * STRA2 + q1] = (unsigned short)(v1 >> 16);
            A_sh[pb * STRA2 + q2] = (unsigned short)(v2 >> 16);
        }
        __syncthreads();  // B2
    }

    // final linear + sigmoid, block 0 (A_sh h-part holds full final h2)
    if (j == 0) {
        if (tid < 256) {
            int b = tid >> 4, kc = tid & 15;
            float pacc = 0.f;
#pragma unroll
            for (int k = 0; k < 16; ++k)
                pacc += bf2f(A_sh[b * STRA2 + kc * 16 + k]) * Wlin[kc * 16 + k];
            red[b * 16 + kc] = pacc;
        }
        __syncthreads();
        if (tid < 16) {
            float ssum = blin[0];
#pragma unroll
            for (int kc = 0; kc < 16; ++kc) ssum += red[tid * 16 + kc];
            out[tid] = 1.0f / (1.0f + __expf(-ssum));
        }
    }
}

// ---------------- host ----------------
extern "C" void kernel_launch(void* const* d_in, const int* in_sizes, int n_in,
                              void* d_out, int out_size, void* d_ws, size_t ws_size,
                              hipStream_t stream) {
    const float* x    = (const float*)d_in[0];
    const int*   flg  = (const int*)d_in[1];
    const float* Wih1 = (const float*)d_in[2];
    const float* Whh1 = (const float*)d_in[3];
    const float* bih1 = (const float*)d_in[4];
    const float* bhh1 = (const float*)d_in[5];
    const float* Wih2 = (const float*)d_in[6];
    const float* Whh2 = (const float*)d_in[7];
    const float* bih2 = (const float*)d_in[8];
    const float* bhh2 = (const float*)d_in[9];
    const float* Wlin = (const float*)d_in[10];
    const float* blin = (const float*)d_in[11];
    float* out = (float*)d_out;

    // workspace layout (ushort units; uint regions 4B-aligned)
    unsigned short* ws   = (unsigned short*)d_ws;
    unsigned short* Bp1  = ws;                       // 2*64*9*64*8  = 589824 ush
    unsigned short* Bp2  = Bp1 + 589824;             // 64*16*64*8   = 524288 ush
    unsigned short* h1bf = Bp2 + 524288;             // 32*16*256    = 131072 ush
    unsigned*       hxS1 = (unsigned*)(h1bf + 131072);  // 262144 uints
    unsigned*       hxF1 = hxS1 + 262144;               // 262144 uints
    unsigned*       hx2S = hxF1 + 262144;               // 8192 uints
    unsigned*       hx2F = hx2S + 8192;                 // 8192 uints
    // total ~= 4.65 MB

    // invalidate all exchange tags for this launch (captured in the graph)
    hipMemsetAsync(hxS1, 0, (size_t)(262144 * 2 + 8192 * 2) * 4, stream);

    pack_w1<<<dim3(288), dim3(256), 0, stream>>>(Wih1, Whh1, Bp1);
    pack_w2<<<dim3(256), dim3(256), 0, stream>>>(Wih2, Whh2, Bp2);
    lstm_layer1<<<dim3(128), dim3(1024), 0, stream>>>(x, flg, bih1, bhh1, Bp1, h1bf, hxS1, hxF1);
    lstm_layer2<<<dim3(32), dim3(1024), 0, stream>>>(h1bf, bih2, bhh2, Bp2, Wlin, blin, out, hx2S, hx2F);
}

// Round 7
// 575.258 us; speedup vs baseline: 2.0153x; 1.0880x over previous
//
#include <hip/hip_runtime.h>
#include <hip/hip_bf16.h>

// Sizes from the reference
#define NSEQ   32
#define SEQLEN 256
#define NB     16    // batch
#define NIN    32
#define NH     256
#define G4     1024  // 4*H

#define PROBE_T 2    // steps using dual-publish + probe before consensus

typedef __attribute__((ext_vector_type(8))) short bf16x8;
typedef __attribute__((ext_vector_type(4))) float f32x4;
typedef unsigned long long ull;

__device__ __forceinline__ unsigned short f2bf(float f) {
    union { float f; unsigned u; } v; v.f = f;
    unsigned u = v.u;
    return (unsigned short)((u + 0x7FFFu + ((u >> 16) & 1u)) >> 16);  // RNE
}
__device__ __forceinline__ float bf2f(unsigned short u) {
    union { unsigned u; float f; } v; v.u = ((unsigned)u) << 16; return v.f;
}
__device__ __forceinline__ float sigf(float x) { return 1.0f / (1.0f + __expf(-x)); }
__device__ __forceinline__ float tanhfast(float x) { return 1.0f - 2.0f / (__expf(2.0f * x) + 1.0f); }

// ---------------- Prologue: pack weights into MFMA B-fragment layout ----------------
__global__ void pack_w1(const float* __restrict__ Wih, const float* __restrict__ Whh,
                        unsigned short* __restrict__ Bp) {
    int idx = blockIdx.x * blockDim.x + threadIdx.x;
    if (idx >= 2 * 64 * 9 * 64) return;
    int fl   = idx / (64 * 9 * 64);
    int rem  = idx % (64 * 9 * 64);
    int tile = rem / (9 * 64);
    int kk   = (rem / 64) % 9;
    int l    = rem & 63;
    int n    = tile * 16 + (l & 15);
    int k0   = kk * 32 + (l >> 4) * 8;
    unsigned short* dst = Bp + (size_t)idx * 8;
#pragma unroll
    for (int j = 0; j < 8; ++j) {
        int k = k0 + j;
        float v = (k < NH) ? Whh[((size_t)fl * G4 + n) * NH + k]
                           : Wih[((size_t)fl * G4 + n) * NIN + (k - NH)];
        dst[j] = f2bf(v);
    }
}

__global__ void pack_w2(const float* __restrict__ Wih, const float* __restrict__ Whh,
                        unsigned short* __restrict__ Bp) {
    int idx = blockIdx.x * blockDim.x + threadIdx.x;
    if (idx >= 64 * 16 * 64) return;
    int tile = idx / (16 * 64);
    int kk   = (idx / 64) % 16;
    int l    = idx & 63;
    int n    = tile * 16 + (l & 15);
    int k0   = kk * 32 + (l >> 4) * 8;
    unsigned short* dst = Bp + (size_t)idx * 8;
#pragma unroll
    for (int j = 0; j < 8; ++j) {
        int k = k0 + j;
        float v = (k < NH) ? Whh[(size_t)n * NH + k] : Wih[(size_t)n * NH + (k - NH)];
        dst[j] = f2bf(v);
    }
}

// ---------------- Layer 1: 4 blocks/seq, consensus-gated L2 exchange ----------------
// bid = j*32 + s -> 4 blocks of seq s share XCD s%8 (perf heuristic; validated at runtime).
// t < PROBE_T: dual publish (F: plain store->L2, S: AGENT atomic->MALL), probe F w/ budget,
//              fall back to S, record failures. After t=PROBE_T-1: 4 blocks exchange
//              verdicts via MALL (guaranteed); if all-F -> pure-F forever (placement is
//              static per launch), else keep dual-publish + per-thread sticky mode.
#define STRA 320                   // Ash row stride in ushorts; 640B = 5*128B
#define ASH_BYTES (NB * STRA * 2)  // 10240

__device__ __forceinline__ unsigned aoff(int row, int col) {  // swizzled byte offset
    return (((unsigned)(row * STRA + col)) * 2u) ^ (((unsigned)row & 7u) << 4);
}

__global__ __launch_bounds__(1024) void lstm_layer1(
    const float* __restrict__ x, const int* __restrict__ flags,
    const float* __restrict__ bih, const float* __restrict__ bhh,
    const unsigned short* __restrict__ Bp_all,
    unsigned short* __restrict__ h1bf,
    unsigned* __restrict__ hxS,    // [NSEQ][2][NB][256] tagged uints (MALL path)
    unsigned* __restrict__ hxF,    // [NSEQ][2][NB][256] tagged uints (L2 path)
    unsigned* __restrict__ vslot)  // [NSEQ][4] verdicts
{
    __shared__ __align__(16) unsigned char Ash[ASH_BYTES];  // [h(256)|x(32)] swizzled
    __shared__ float gate[4][64][17];
    __shared__ int s_fail, s_groupF;

    const int bid = blockIdx.x;
    const int s   = bid & 31;
    const int j   = bid >> 5;
    const int tid = threadIdx.x;
    const int w = tid >> 6, l = tid & 63, lr = l & 15, kg = l >> 4;
    const int g = w >> 2, cg = w & 3;
    const int fl = flags[s];
    const int tile = g * 16 + j * 4 + cg;
    const unsigned short* Bp = Bp_all + (size_t)fl * (64 * 9 * 64 * 8);

    bf16x8 wreg[9];
#pragma unroll
    for (int kk = 0; kk < 9; ++kk)
        wreg[kk] = *(const bf16x8*)(Bp + ((size_t)(tile * 9 + kk) * 64 + l) * 8);

    const int grow = tile * 16 + lr;
    const float bias = bih[fl * G4 + grow] + bhh[fl * G4 + grow];

    const int pb = tid >> 6, pc = tid & 63;   // epilogue/post/readback: (batch, local col)
    const int o0 = (((j + 1) & 3) << 6) + pc; // the 3 peer column slots
    const int o1 = (((j + 2) & 3) << 6) + pc;
    const int o2 = (((j + 3) & 3) << 6) + pc;
    const int xb = tid >> 5, xk = tid & 31;   // x staging (tid < 512)
    float cst = 0.f;
    int mode = 0;       // sticky per-thread (non-consensus path): 0 probe, 1 F, 2 S
    bool groupF = false;

    unsigned* hxSs = hxS + (size_t)s * (2 * NB * 256);
    unsigned* hxFs = hxF + (size_t)s * (2 * NB * 256);

    if (tid == 0) { s_fail = 0; s_groupF = 0; }
    for (int i = tid * 4; i < ASH_BYTES; i += 1024 * 4)
        *(unsigned*)(Ash + i) = 0u;
    __syncthreads();
    if (tid < NB * NIN)
        *(unsigned short*)(Ash + aoff(xb, NH + xk)) =
            f2bf(x[(((size_t)s * SEQLEN) * NB + xb) * NIN + xk]);
    __syncthreads();

    for (int t = 0; t < SEQLEN; ++t) {
        float xpre = 0.f;
        if (t + 1 < SEQLEN && tid < NB * NIN)
            xpre = x[(((size_t)s * SEQLEN + t + 1) * NB + xb) * NIN + xk];

        // MFMA: two independent chains
        f32x4 acc = {bias, bias, bias, bias};
        f32x4 accB = {0.f, 0.f, 0.f, 0.f};
#pragma unroll
        for (int kk = 0; kk < 5; ++kk) {
            bf16x8 a = *(const bf16x8*)(Ash + aoff(lr, kk * 32 + kg * 8));
            acc = __builtin_amdgcn_mfma_f32_16x16x32_bf16(a, wreg[kk], acc, 0, 0, 0);
        }
#pragma unroll
        for (int kk = 5; kk < 9; ++kk) {
            bf16x8 a = *(const bf16x8*)(Ash + aoff(lr, kk * 32 + kg * 8));
            accB = __builtin_amdgcn_mfma_f32_16x16x32_bf16(a, wreg[kk], accB, 0, 0, 0);
        }
#pragma unroll
        for (int r = 0; r < 4; ++r)
            gate[g][cg * 16 + lr][kg * 4 + r] = acc[r] + accB[r];
        __syncthreads();  // B1: gates ready, all Ash reads of step t done

        // epilogue: 1 thread = 1 (batch, col)
        float ig = gate[0][pc][pb], fg = gate[1][pc][pb];
        float gg = gate[2][pc][pb], og = gate[3][pc][pb];
        float cn = sigf(fg) * cst + sigf(ig) * tanhfast(gg);
        cst = cn;
        float h = sigf(og) * tanhfast(cn);
        unsigned short hb = f2bf(h);
        *(unsigned short*)(Ash + aoff(pb, (j << 6) + pc)) = hb;  // own col -> LDS

        if (t == SEQLEN - 1) {
            h1bf[((size_t)s * NB + pb) * NH + (j << 6) + pc] = hb;
        } else {
            const unsigned tg = (unsigned)(t + 1);
            const unsigned word = ((unsigned)hb << 16) | tg;
            const size_t ro = (size_t)((((t + 1) & 1) * NB + pb) << 8);
            unsigned* rowF = hxFs + ro;
            unsigned* rowS = hxSs + ro;
            volatile const unsigned* F = rowF;

            rowF[(j << 6) + pc] = word;                     // fast publish (local L2)
            const bool pubS = (t < PROBE_T) || !groupF;
            if (pubS)
                __hip_atomic_store(rowS + (j << 6) + pc, word,
                                   __ATOMIC_RELAXED, __HIP_MEMORY_SCOPE_AGENT);
            // issue initial F loads early, then overlap with x staging
            unsigned v0 = F[o0], v1 = F[o1], v2 = F[o2];
            if (tid < NB * NIN)
                *(unsigned short*)(Ash + aoff(xb, NH + xk)) = f2bf(xpre);

            if (groupF) {
                // consensus pure-F: placement static -> F always delivers
                while ((v0 & 0xFFFFu) != tg) v0 = F[o0];
                while ((v1 & 0xFFFFu) != tg) v1 = F[o1];
                while ((v2 & 0xFFFFu) != tg) v2 = F[o2];
            } else {
                bool ok = false;
                if (mode != 2) {
                    int budget = (mode == 0) ? 300 : 4000;
                    while ((v0 & 0xFFFFu) != tg && budget-- > 0) v0 = F[o0];
                    while ((v1 & 0xFFFFu) != tg && budget-- > 0) v1 = F[o1];
                    while ((v2 & 0xFFFFu) != tg && budget-- > 0) v2 = F[o2];
                    ok = ((v0 & 0xFFFFu) == tg) && ((v1 & 0xFFFFu) == tg) && ((v2 & 0xFFFFu) == tg);
                    if (t >= PROBE_T) mode = ok ? 1 : 2;
                }
                if (!ok) {
                    if (t < PROBE_T) s_fail = 1;  // benign race, same value
                    v0 = __hip_atomic_load(rowS + o0, __ATOMIC_RELAXED, __HIP_MEMORY_SCOPE_AGENT);
                    v1 = __hip_atomic_load(rowS + o1, __ATOMIC_RELAXED, __HIP_MEMORY_SCOPE_AGENT);
                    v2 = __hip_atomic_load(rowS + o2, __ATOMIC_RELAXED, __HIP_MEMORY_SCOPE_AGENT);
                    while ((v0 & 0xFFFFu) != tg)
                        v0 = __hip_atomic_load(rowS + o0, __ATOMIC_RELAXED, __HIP_MEMORY_SCOPE_AGENT);
                    while ((v1 & 0xFFFFu) != tg)
                        v1 = __hip_atomic_load(rowS + o1, __ATOMIC_RELAXED, __HIP_MEMORY_SCOPE_AGENT);
                    while ((v2 & 0xFFFFu) != tg)
                        v2 = __hip_atomic_load(rowS + o2, __ATOMIC_RELAXED, __HIP_MEMORY_SCOPE_AGENT);
                }
            }
            *(unsigned short*)(Ash + aoff(pb, o0)) = (unsigned short)(v0 >> 16);
            *(unsigned short*)(Ash + aoff(pb, o1)) = (unsigned short)(v1 >> 16);
            *(unsigned short*)(Ash + aoff(pb, o2)) = (unsigned short)(v2 >> 16);
            __syncthreads();  // B2: Ash complete for step t+1

            if (t == PROBE_T - 1) {
                // group consensus via MALL (guaranteed delivery)
                if (tid == 0) {
                    unsigned verdict = (s_fail == 0) ? 2u : 1u;
                    __hip_atomic_store(vslot + s * 4 + j, verdict,
                                       __ATOMIC_RELAXED, __HIP_MEMORY_SCOPE_AGENT);
                    unsigned a0, a1, a2, a3;
                    do {
                        a0 = __hip_atomic_load(vslot + s * 4 + 0, __ATOMIC_RELAXED, __HIP_MEMORY_SCOPE_AGENT);
                        a1 = __hip_atomic_load(vslot + s * 4 + 1, __ATOMIC_RELAXED, __HIP_MEMORY_SCOPE_AGENT);
                        a2 = __hip_atomic_load(vslot + s * 4 + 2, __ATOMIC_RELAXED, __HIP_MEMORY_SCOPE_AGENT);
                        a3 = __hip_atomic_load(vslot + s * 4 + 3, __ATOMIC_RELAXED, __HIP_MEMORY_SCOPE_AGENT);
                    } while (!(a0 && a1 && a2 && a3));
                    s_groupF = (a0 == 2u && a1 == 2u && a2 == 2u && a3 == 2u) ? 1 : 0;
                }
                __syncthreads();  // B3 (once per kernel)
                groupF = (s_groupF != 0);
            }
        }
    }
}

// ---------------- Layer 2: 4 blocks (grid 32, bid%8==0 -> same XCD), 32-step scan ----------------
#define STRA2 520  // 512 data + 8 pad

__global__ __launch_bounds__(1024) void lstm_layer2(
    const unsigned short* __restrict__ h1bf,
    const float* __restrict__ bih2, const float* __restrict__ bhh2,
    const unsigned short* __restrict__ Bp2,
    const float* __restrict__ Wlin, const float* __restrict__ blin,
    float* __restrict__ out,
    unsigned* __restrict__ hx2S,   // [2][NB][256] tagged uints (MALL)
    unsigned* __restrict__ hx2F,   // [2][NB][256] tagged uints (L2)
    unsigned* __restrict__ vslot2) // [4]
{
    const int bid = blockIdx.x;
    if (bid & 7) return;
    const int j = bid >> 3;  // 0..3

    __shared__ __align__(16) unsigned short A_sh[NB * STRA2];  // [h2(256)|h1_s(256)]
    __shared__ float gate[4][64][17];
    __shared__ float red[NB * 16];
    __shared__ int s_fail, s_groupF;

    const int tid = threadIdx.x;
    const int w = tid >> 6, l = tid & 63, lr = l & 15, kg = l >> 4;
    const int g = w >> 2, cg = w & 3;
    const int tile = g * 16 + j * 4 + cg;

    bf16x8 wreg[16];
#pragma unroll
    for (int kk = 0; kk < 16; ++kk)
        wreg[kk] = *(const bf16x8*)(Bp2 + ((size_t)(tile * 16 + kk) * 64 + l) * 8);

    const int grow = tile * 16 + lr;
    const float bias = bih2[grow] + bhh2[grow];
    const int pb = tid >> 6, pc = tid & 63;          // epilogue: 1 col per thread
    float cst = 0.f;
    int mode = 0;
    bool groupF = false;
    const int rb = tid >> 6, rc4 = (tid & 63) * 4;   // h1 staging: 4 cols per thread
    const int q0 = (((j + 1) & 3) << 6) + pc;
    const int q1 = (((j + 2) & 3) << 6) + pc;
    const int q2 = (((j + 3) & 3) << 6) + pc;

    if (tid == 0) { s_fail = 0; s_groupF = 0; }
    for (int i = tid; i < NB * NH; i += 1024)
        A_sh[(i >> 8) * STRA2 + (i & 255)] = 0;
    *(ushort4*)&A_sh[rb * STRA2 + NH + rc4] = *(const ushort4*)&h1bf[(size_t)rb * NH + rc4];
    __syncthreads();

    for (int sq = 0; sq < NSEQ; ++sq) {
        ushort4 pre = {0, 0, 0, 0};
        if (sq + 1 < NSEQ)
            pre = *(const ushort4*)&h1bf[((size_t)(sq + 1) * NB + rb) * NH + rc4];

        f32x4 acc = {bias, bias, bias, bias};
        f32x4 accB = {0.f, 0.f, 0.f, 0.f};
#pragma unroll
        for (int kk = 0; kk < 8; ++kk) {
            bf16x8 a = *(const bf16x8*)&A_sh[lr * STRA2 + kk * 32 + kg * 8];
            acc = __builtin_amdgcn_mfma_f32_16x16x32_bf16(a, wreg[kk], acc, 0, 0, 0);
        }
#pragma unroll
        for (int kk = 8; kk < 16; ++kk) {
            bf16x8 a = *(const bf16x8*)&A_sh[lr * STRA2 + kk * 32 + kg * 8];
            accB = __builtin_amdgcn_mfma_f32_16x16x32_bf16(a, wreg[kk], accB, 0, 0, 0);
        }
#pragma unroll
        for (int r = 0; r < 4; ++r)
            gate[g][cg * 16 + lr][kg * 4 + r] = acc[r] + accB[r];
        __syncthreads();  // B1

        const unsigned tg = (unsigned)(sq + 1);
        const size_t ro = (size_t)((((sq + 1) & 1) * NB + pb) << 8);
        unsigned* rowF = hx2F + ro;
        unsigned* rowS = hx2S + ro;
        volatile const unsigned* F = rowF;
        {
            float ig = gate[0][pc][pb], fg = gate[1][pc][pb];
            float gg = gate[2][pc][pb], og = gate[3][pc][pb];
            float cn = sigf(fg) * cst + sigf(ig) * tanhfast(gg);
            cst = cn;
            float h = sigf(og) * tanhfast(cn);
            unsigned word = ((unsigned)f2bf(h) << 16) | tg;
            A_sh[pb * STRA2 + (j << 6) + pc] = (unsigned short)(word >> 16);
            rowF[(j << 6) + pc] = word;
            if ((sq < PROBE_T) || !groupF)
                __hip_atomic_store(rowS + (j << 6) + pc, word,
                                   __ATOMIC_RELAXED, __HIP_MEMORY_SCOPE_AGENT);
        }
        unsigned v0 = F[q0], v1 = F[q1], v2 = F[q2];
        if (sq + 1 < NSEQ)
            *(ushort4*)&A_sh[rb * STRA2 + NH + rc4] = pre;

        if (groupF) {
            while ((v0 & 0xFFFFu) != tg) v0 = F[q0];
            while ((v1 & 0xFFFFu) != tg) v1 = F[q1];
            while ((v2 & 0xFFFFu) != tg) v2 = F[q2];
        } else {
            bool ok = false;
            if (mode != 2) {
                int budget = (mode == 0) ? 300 : 4000;
                while ((v0 & 0xFFFFu) != tg && budget-- > 0) v0 = F[q0];
                while ((v1 & 0xFFFFu) != tg && budget-- > 0) v1 = F[q1];
                while ((v2 & 0xFFFFu) != tg && budget-- > 0) v2 = F[q2];
                ok = ((v0 & 0xFFFFu) == tg) && ((v1 & 0xFFFFu) == tg) && ((v2 & 0xFFFFu) == tg);
                if (sq >= PROBE_T) mode = ok ? 1 : 2;
            }
            if (!ok) {
                if (sq < PROBE_T) s_fail = 1;
                v0 = __hip_atomic_load(rowS + q0, __ATOMIC_RELAXED, __HIP_MEMORY_SCOPE_AGENT);
                v1 = __hip_atomic_load(rowS + q1, __ATOMIC_RELAXED, __HIP_MEMORY_SCOPE_AGENT);
                v2 = __hip_atomic_load(rowS + q2, __ATOMIC_RELAXED, __HIP_MEMORY_SCOPE_AGENT);
                while ((v0 & 0xFFFFu) != tg)
                    v0 = __hip_atomic_load(rowS + q0, __ATOMIC_RELAXED, __HIP_MEMORY_SCOPE_AGENT);
                while ((v1 & 0xFFFFu) != tg)
                    v1 = __hip_atomic_load(rowS + q1, __ATOMIC_RELAXED, __HIP_MEMORY_SCOPE_AGENT);
                while ((v2 & 0xFFFFu) != tg)
                    v2 = __hip_atomic_load(rowS + q2, __ATOMIC_RELAXED, __HIP_MEMORY_SCOPE_AGENT);
            }
        }
        A_sh[pb * STRA2 + q0] = (unsigned short)(v0 >> 16);
        A_sh[pb * STRA2 + q1] = (unsigned short)(v1 >> 16);
        A_sh[pb * STRA2 + q2] = (unsigned short)(v2 >> 16);
        __syncthreads();  // B2

        if (sq == PROBE_T - 1) {
            if (tid == 0) {
                unsigned verdict = (s_fail == 0) ? 2u : 1u;
                __hip_atomic_store(vslot2 + j, verdict, __ATOMIC_RELAXED, __HIP_MEMORY_SCOPE_AGENT);
                unsigned a0, a1, a2, a3;
                do {
                    a0 = __hip_atomic_load(vslot2 + 0, __ATOMIC_RELAXED, __HIP_MEMORY_SCOPE_AGENT);
                    a1 = __hip_atomic_load(vslot2 + 1, __ATOMIC_RELAXED, __HIP_MEMORY_SCOPE_AGENT);
                    a2 = __hip_atomic_load(vslot2 + 2, __ATOMIC_RELAXED, __HIP_MEMORY_SCOPE_AGENT);
                    a3 = __hip_atomic_load(vslot2 + 3, __ATOMIC_RELAXED, __HIP_MEMORY_SCOPE_AGENT);
                } while (!(a0 && a1 && a2 && a3));
                s_groupF = (a0 == 2u && a1 == 2u && a2 == 2u && a3 == 2u) ? 1 : 0;
            }
            __syncthreads();
            groupF = (s_groupF != 0);
        }
    }

    // final linear + sigmoid, block 0 (A_sh h-part holds full final h2)
    if (j == 0) {
        if (tid < 256) {
            int b = tid >> 4, kc = tid & 15;
            float pacc = 0.f;
#pragma unroll
            for (int k = 0; k < 16; ++k)
                pacc += bf2f(A_sh[b * STRA2 + kc * 16 + k]) * Wlin[kc * 16 + k];
            red[b * 16 + kc] = pacc;
        }
        __syncthreads();
        if (tid < 16) {
            float ssum = blin[0];
#pragma unroll
            for (int kc = 0; kc < 16; ++kc) ssum += red[tid * 16 + kc];
            out[tid] = 1.0f / (1.0f + __expf(-ssum));
        }
    }
}

// ---------------- host ----------------
extern "C" void kernel_launch(void* const* d_in, const int* in_sizes, int n_in,
                              void* d_out, int out_size, void* d_ws, size_t ws_size,
                              hipStream_t stream) {
    const float* x    = (const float*)d_in[0];
    const int*   flg  = (const int*)d_in[1];
    const float* Wih1 = (const float*)d_in[2];
    const float* Whh1 = (const float*)d_in[3];
    const float* bih1 = (const float*)d_in[4];
    const float* bhh1 = (const float*)d_in[5];
    const float* Wih2 = (const float*)d_in[6];
    const float* Whh2 = (const float*)d_in[7];
    const float* bih2 = (const float*)d_in[8];
    const float* bhh2 = (const float*)d_in[9];
    const float* Wlin = (const float*)d_in[10];
    const float* blin = (const float*)d_in[11];
    float* out = (float*)d_out;

    // workspace layout (ushort units; uint regions 4B-aligned)
    unsigned short* ws   = (unsigned short*)d_ws;
    unsigned short* Bp1  = ws;                       // 2*64*9*64*8  = 589824 ush
    unsigned short* Bp2  = Bp1 + 589824;             // 64*16*64*8   = 524288 ush
    unsigned short* h1bf = Bp2 + 524288;             // 32*16*256    = 131072 ush
    unsigned*       hxS1 = (unsigned*)(h1bf + 131072);  // 262144 uints
    unsigned*       hxF1 = hxS1 + 262144;               // 262144 uints
    unsigned*       hx2S = hxF1 + 262144;               // 8192 uints
    unsigned*       hx2F = hx2S + 8192;                 // 8192 uints
    unsigned*       vs1  = hx2F + 8192;                 // 128 uints
    unsigned*       vs2  = vs1 + 128;                   // 4 uints
    // total ~= 4.65 MB

    // invalidate all exchange tags + verdicts for this launch (captured in graph)
    hipMemsetAsync(hxS1, 0, (size_t)(262144 * 2 + 8192 * 2 + 132) * 4, stream);

    pack_w1<<<dim3(288), dim3(256), 0, stream>>>(Wih1, Whh1, Bp1);
    pack_w2<<<dim3(256), dim3(256), 0, stream>>>(Wih2, Whh2, Bp2);
    lstm_layer1<<<dim3(128), dim3(1024), 0, stream>>>(x, flg, bih1, bhh1, Bp1, h1bf,
                                                      hxS1, hxF1, vs1);
    lstm_layer2<<<dim3(32), dim3(1024), 0, stream>>>(h1bf, bih2, bhh2, Bp2, Wlin, blin, out,
                                                     hx2S, hx2F, vs2);
}